// Round 13
// baseline (103.890 us; speedup 1.0000x reference)
//
#include <hip/hip_runtime.h>
#include <hip/hip_bf16.h>

#define NB 4
#define NH 12
#define NS 2048
#define PD 64
#define CHUNK 16640   // Kf16 frag-major 8192 + Vt f16 frag-major 8192 + cb' 256
#define LOG2E 1.4426950408889634f

typedef float f32x4  __attribute__((ext_vector_type(4)));
typedef float f32x16 __attribute__((ext_vector_type(16)));
typedef short s16x8  __attribute__((ext_vector_type(8)));
typedef _Float16 h16x8 __attribute__((ext_vector_type(8)));
typedef __fp16 fp16x2 __attribute__((ext_vector_type(2)));
typedef unsigned int u32x2 __attribute__((ext_vector_type(2)));

#define MFMAH(a, b, c) __builtin_amdgcn_mfma_f32_32x32x16_f16((a), (b), (c), 0, 0, 0)
#define MFMAB(a, b, c) __builtin_amdgcn_mfma_f32_32x32x16_bf16((a), (b), (c), 0, 0, 0)

static __device__ __forceinline__ unsigned short bfbits(float x) {
    __hip_bfloat16 h = __float2bfloat16(x);
    union { __hip_bfloat16 b; unsigned short u; } c; c.b = h; return c.u;
}
static __device__ __forceinline__ float bf2f(unsigned short u) {
    union { unsigned int i; float f; } c; c.i = ((unsigned int)u) << 16; return c.f;
}
static __device__ __forceinline__ unsigned short hbits(float x) {
    union { _Float16 h; unsigned short u; } c; c.h = (_Float16)x; return c.u;
}
static __device__ __forceinline__ float dot4(const float4& a) {
    return fmaf(a.x, a.x, fmaf(a.y, a.y, fmaf(a.z, a.z, a.w * a.w)));
}
static __device__ __forceinline__ uint2 cvt4f16(float4 v) {
    uint2 r;
    r.x = (unsigned)hbits(v.x) | ((unsigned)hbits(v.y) << 16);
    r.y = (unsigned)hbits(v.z) | ((unsigned)hbits(v.w) << 16);
    return r;
}
static __device__ __forceinline__ uint2 cvt4h(float4 v) {
    uint2 h4;
    h4.x = (unsigned)bfbits(v.x) | ((unsigned)bfbits(v.y) << 16);
    h4.y = (unsigned)bfbits(v.z) | ((unsigned)bfbits(v.w) << 16);
    return h4;
}
static __device__ __forceinline__ void split4(float4 v, uint2& h4, uint2& l4) {
    unsigned short h0 = bfbits(v.x), h1 = bfbits(v.y), h2 = bfbits(v.z), h3 = bfbits(v.w);
    unsigned short l0 = bfbits(v.x - bf2f(h0)), l1 = bfbits(v.y - bf2f(h1));
    unsigned short l2 = bfbits(v.z - bf2f(h2)), l3 = bfbits(v.w - bf2f(h3));
    h4.x = (unsigned)h0 | ((unsigned)h1 << 16); h4.y = (unsigned)h2 | ((unsigned)h3 << 16);
    l4.x = (unsigned)l0 | ((unsigned)l1 << 16); l4.y = (unsigned)l2 | ((unsigned)l3 << 16);
}
static __device__ __forceinline__ unsigned int pk2(float a, float b) {
    return (unsigned)bfbits(a) | ((unsigned)bfbits(b) << 16);
}
static __device__ __forceinline__ unsigned int pk2h(float a, float b) {
#if __has_builtin(__builtin_amdgcn_cvt_pkrtz)
    union { fp16x2 h; unsigned u; } c;
    c.h = __builtin_amdgcn_cvt_pkrtz(a, b);
    return c.u;
#else
    return (unsigned)hbits(a) | ((unsigned)hbits(b) << 16);
#endif
}
static __device__ __forceinline__ float fexp2(float x) {
#if __has_builtin(__builtin_amdgcn_exp2f)
    return __builtin_amdgcn_exp2f(x);
#else
    return exp2f(x);
#endif
}
// frag-major LDS read (prologue Q): [g][row(64)][8 ushort]
static __device__ __forceinline__ h16x8 ldfm(const unsigned short* base, int g, int row) {
    return *(const h16x8*)&base[(g * 64 + row) * 8];
}
// legacy swizzled read (fallback kernel)
static __device__ __forceinline__ s16x8 ldfrag(const unsigned short* s, int row, int kc) {
    return *(const s16x8*)&s[(row * 64 + kc) ^ ((row & 7) << 3)];
}
static __device__ __forceinline__ void pswap(unsigned int& a, unsigned int& b) {
#if __has_builtin(__builtin_amdgcn_permlane32_swap)
    u32x2 r = __builtin_amdgcn_permlane32_swap(a, b, false, false);
    a = r[0]; b = r[1];
#else
    const unsigned ax = (unsigned)__shfl_xor((int)a, 32);
    const unsigned bx = (unsigned)__shfl_xor((int)b, 32);
    const bool hi = (threadIdx.x & 32) != 0;
    const unsigned na = hi ? bx : a;
    const unsigned nb = hi ? b : ax;
    a = na; b = nb;
#endif
}
static __device__ __forceinline__ h16x8 as_h(uint4 u) {
    union { uint4 u; h16x8 h; } c; c.u = u; return c.h;
}

// ---------------- precompute: frag-major f16 K(xlog2e)/Vt + cb' chunks (unchanged) ----------------
__global__ __launch_bounds__(256, 4) void kde_pre(
    const float* __restrict__ Kg, const float* __restrict__ Vg,
    const float* __restrict__ maskg, unsigned char* __restrict__ ws)
{
    const int t    = threadIdx.x;
    const int lane = t & 63;
    const int w    = t >> 6;

    const int s   = blockIdx.x;
    const int xcd = s & 7;
    const int ii  = s >> 3;
    const int bh  = 6 * xcd + (ii >> 5);
    const int mt  = ii & 31;
    const int b   = bh / NH;
    const int m0  = mt * 64;

    const float DN = 0.42044820762685725f;

    const float* Kh = Kg + (size_t)bh * NS * PD;
    const float* Vh = Vg + (size_t)bh * NS * PD;
    const float* mk = maskg + (size_t)b * NS;

    unsigned char* ch = ws + (size_t)(bh * 32 + mt) * CHUNK;
    unsigned short* gK  = (unsigned short*)ch;
    unsigned short* gVt = gK + 4096;
    float* gcb = (float*)(ch + 16384);

    #pragma unroll
    for (int j = 0; j < 4; ++j) {
        const int idx = j * 256 + t;
        const int row = idx >> 4;
        const int u   = idx & 15;
        const float mr  = mk[m0 + row];
        const float ksc = mr * DN;
        float4 v = *(const float4*)(Kh + (size_t)(m0 + row) * PD + 4 * u);
        v.x *= ksc; v.y *= ksc; v.z *= ksc; v.w *= ksc;
        float d = dot4(v);
        float4 vl = make_float4(v.x * LOG2E, v.y * LOG2E, v.z * LOG2E, v.w * LOG2E);
        *(uint2*)&gK[((u >> 1) * 64 + row) * 8 + 4 * (u & 1)] = cvt4f16(vl);
        d += __shfl_xor(d, 1); d += __shfl_xor(d, 2);
        d += __shfl_xor(d, 4); d += __shfl_xor(d, 8);
        if (u == 0) gcb[row] = fmaf(-1.0e9f, 1.f - mr, -0.5f * d) * LOG2E;
    }
    #pragma unroll
    for (int j = 0; j < 4; ++j) {
        const int p  = lane;
        const int mq = 4 * j + ((w + (p >> 3)) & 3);
        const float* vc = Vh + (size_t)(m0 + 4 * mq) * PD + p;
        float4 mr = *(const float4*)&mk[m0 + 4 * mq];
        float4 v = make_float4(vc[0] * (mr.x * DN), vc[PD] * (mr.y * DN),
                               vc[2 * PD] * (mr.z * DN), vc[3 * PD] * (mr.w * DN));
        *(uint2*)&gVt[((mq >> 1) * 64 + p) * 8 + 4 * (mq & 1)] = cvt4f16(v);
    }
}

// ---------------- main: global->register streaming, no loop LDS, no loop barriers ----------------
__global__ __launch_bounds__(256) void kde_main(
    const float* __restrict__ Qg, const float* __restrict__ maskg,
    const unsigned char* __restrict__ ws, float* __restrict__ Xg)
{
    __shared__ __align__(16) float sXf[64 * 64];   // epilogue; aliased as Q stage in prologue
    __shared__ float sdQ[64], red[4];

    unsigned short* const sQ = (unsigned short*)sXf;   // 8 KB frag-major f16 Q

    const int t    = threadIdx.x;
    const int lane = t & 63;
    const int w    = t >> 6;
    const int h    = lane >> 5;
    const int c    = lane & 31;
    const int wm   = w >> 1;
    const int wq   = w & 1;

    // XCD-bijective remap: 1536 blocks = 8 XCD * (6 bh * 32 qb)
    const int s   = blockIdx.x;
    const int xcd = s & 7;
    const int ii  = s >> 3;
    const int bh  = 6 * xcd + (ii >> 5);
    const int n0  = (ii & 31) * 64;
    const int b   = bh / NH;

    const float DN = 0.42044820762685725f;

    const float* Qh = Qg + (size_t)bh * NS * PD;
    const float* mk = maskg + (size_t)b * NS;
    const unsigned char* chb = ws + (size_t)bh * 32 * CHUNK;

    // ---- npn ----
    {
        float sm = 0.f;
        for (int i = t; i < NS; i += 256) sm += mk[i];
        #pragma unroll
        for (int m = 1; m < 64; m <<= 1) sm += __shfl_xor(sm, m);
        if (lane == 0) red[w] = sm;
    }

    // ---- stage Q (scaled, f16, frag-major) + diag_Q ----
    #pragma unroll
    for (int j = 0; j < 4; ++j) {
        const int idx = j * 256 + t;
        const int row = idx >> 4;
        const int u   = idx & 15;
        const float qs = mk[n0 + row] * DN;
        float4 v = *(const float4*)(Qh + (size_t)(n0 + row) * PD + 4 * u);
        v.x *= qs; v.y *= qs; v.z *= qs; v.w *= qs;
        *(uint2*)&sQ[((u >> 1) * 64 + row) * 8 + 4 * (u & 1)] = cvt4f16(v);
        float d = dot4(v);
        d += __shfl_xor(d, 1); d += __shfl_xor(d, 2);
        d += __shfl_xor(d, 4); d += __shfl_xor(d, 8);
        if (u == 0) sdQ[row] = 0.5f * d;
    }
    __syncthreads();

    const float npn  = red[0] + red[1] + red[2] + red[3];
    const float invn = 1.f / npn;

    // ---- hoist Q B-fragments (4 x b128 = 16 VGPR) ----
    h16x8 qb[4];
    #pragma unroll
    for (int ks = 0; ks < 4; ++ks)
        qb[ks] = ldfm(sQ, 2 * ks + h, 32 * wq + c);
    __syncthreads();   // all waves done with sQ before anyone reaches epilogue (sXf alias)

    // ---- per-lane byte offsets into a chunk (fragment addressing) ----
    const int koff  = (h * 64 + 32 * wm + c) * 16;          // K: + ks*2048 (ks 0,1)
    const int koff2 = koff + 4096;                          //    + ks*2048 (ks 2,3)
    const int voff  = 8192 + ((4 * wm + h) * 64 + c) * 16;  // V row c:   + ks2*2048
    const int voff2 = voff + 512;                           // V row 32+c:+ ks2*2048
    const int cboff = 16384 + (32 * wm + 4 * h) * 4;        // cb: + g4*32

    f32x16 xacc[2];
    #pragma unroll
    for (int pt = 0; pt < 2; ++pt)
        #pragma unroll
        for (int r = 0; r < 16; ++r) xacc[pt][r] = 0.f;

#define LOADS(KF, VF, CF, MT) do {                                   \
        const unsigned char* chp_ = chb + (size_t)(MT) * CHUNK;      \
        KF[0] = *(const uint4*)(chp_ + koff);                        \
        KF[1] = *(const uint4*)(chp_ + koff + 2048);                 \
        KF[2] = *(const uint4*)(chp_ + koff2);                       \
        KF[3] = *(const uint4*)(chp_ + koff2 + 2048);                \
        VF[0] = *(const uint4*)(chp_ + voff);                        \
        VF[1] = *(const uint4*)(chp_ + voff2);                       \
        VF[2] = *(const uint4*)(chp_ + voff + 2048);                 \
        VF[3] = *(const uint4*)(chp_ + voff2 + 2048);                \
        CF[0] = *(const f32x4*)(chp_ + cboff);                       \
        CF[1] = *(const f32x4*)(chp_ + cboff + 32);                  \
        CF[2] = *(const f32x4*)(chp_ + cboff + 64);                  \
        CF[3] = *(const f32x4*)(chp_ + cboff + 96);                  \
    } while (0)

#define COMPUTE(KF, VF, CF) do {                                     \
        f32x16 acc_;                                                 \
        _Pragma("unroll")                                            \
        for (int r_ = 0; r_ < 16; ++r_) acc_[r_] = 0.f;              \
        __builtin_amdgcn_s_setprio(1);                               \
        _Pragma("unroll")                                            \
        for (int ks_ = 0; ks_ < 4; ++ks_)                            \
            acc_ = MFMAH(as_h(KF[ks_]), qb[ks_], acc_);              \
        __builtin_amdgcn_s_setprio(0);                               \
        float pv_[16];                                               \
        _Pragma("unroll")                                            \
        for (int g_ = 0; g_ < 4; ++g_) {                             \
            _Pragma("unroll")                                        \
            for (int e_ = 0; e_ < 4; ++e_)                           \
                pv_[4 * g_ + e_] = fexp2(acc_[4 * g_ + e_] + CF[g_][e_]); \
        }                                                            \
        _Pragma("unroll")                                            \
        for (int k2_ = 0; k2_ < 2; ++k2_) {                          \
            const int bb_ = 8 * k2_;                                 \
            unsigned a0_ = pk2h(pv_[bb_ + 0], pv_[bb_ + 1]);         \
            unsigned a1_ = pk2h(pv_[bb_ + 2], pv_[bb_ + 3]);         \
            unsigned a2_ = pk2h(pv_[bb_ + 4], pv_[bb_ + 5]);         \
            unsigned a3_ = pk2h(pv_[bb_ + 6], pv_[bb_ + 7]);         \
            pswap(a0_, a2_); pswap(a1_, a3_);                        \
            union { unsigned u[4]; h16x8 v; } pa_;                   \
            pa_.u[0] = a0_; pa_.u[1] = a1_; pa_.u[2] = a2_; pa_.u[3] = a3_; \
            __builtin_amdgcn_s_setprio(1);                           \
            xacc[0] = MFMAH(pa_.v, as_h(VF[2 * k2_ + 0]), xacc[0]);  \
            xacc[1] = MFMAH(pa_.v, as_h(VF[2 * k2_ + 1]), xacc[1]);  \
            __builtin_amdgcn_s_setprio(0);                           \
        }                                                            \
    } while (0)

    // ---- register-ping-pong streaming loop (no LDS, no barriers) ----
    uint4 k0[4], v0[4], k1[4], v1[4];
    f32x4 c0[4], c1[4];
    LOADS(k0, v0, c0, 0);
    LOADS(k1, v1, c1, 1);
    for (int mt = 0; mt < 30; mt += 2) {
        COMPUTE(k0, v0, c0);
        LOADS(k0, v0, c0, mt + 2);
        COMPUTE(k1, v1, c1);
        LOADS(k1, v1, c1, mt + 3);
    }
    COMPUTE(k0, v0, c0);
    COMPUTE(k1, v1, c1);

#undef LOADS
#undef COMPUTE

    // ---- cross-wave (wm) reduction via LDS; scale by exp2(-dq')*invn; write X ----
    if (wm == 0) {
        #pragma unroll
        for (int pt = 0; pt < 2; ++pt)
            #pragma unroll
            for (int r = 0; r < 16; ++r) {
                const int row = 32 * wq + (r & 3) + 8 * (r >> 2) + 4 * h;
                sXf[row * 64 + 32 * pt + c] = xacc[pt][r];
            }
    }
    __syncthreads();
    if (wm == 1) {
        float* Xh = Xg + (size_t)bh * NS * PD;
        #pragma unroll
        for (int pt = 0; pt < 2; ++pt)
            #pragma unroll
            for (int r = 0; r < 16; ++r) {
                const int row = 32 * wq + (r & 3) + 8 * (r >> 2) + 4 * h;
                const int col = 32 * pt + c;
                const float sc = fexp2(-sdQ[row] * LOG2E) * invn;
                Xh[(size_t)(n0 + row) * PD + col] = (sXf[row * 64 + col] + xacc[pt][r]) * sc;
            }
    }
}

// ---------------- fallback (R6 kernel, bf16 split) if ws too small ----------------
__global__ __launch_bounds__(256, 2) void kde_attn_fb(
    const float* __restrict__ Qg, const float* __restrict__ Kg,
    const float* __restrict__ Vg, const float* __restrict__ maskg,
    float* __restrict__ Xg)
{
    __shared__ __align__(16) unsigned short sKh[4096], sKl[4096], sVt[4096];
    __shared__ __align__(16) unsigned short sU[8192];
    __shared__ __align__(16) float scb[64];
    __shared__ float sdQ[64], red[4];

    unsigned short* const sQh = sU;
    unsigned short* const sQl = sU + 4096;

    const int t    = threadIdx.x;
    const int lane = t & 63;
    const int w    = t >> 6;
    const int h    = lane >> 5;
    const int c    = lane & 31;
    const int wm   = w >> 1;
    const int wq   = w & 1;

    const int s   = blockIdx.x;
    const int xcd = s & 7;
    const int ii  = s >> 3;
    const int bh  = 6 * xcd + (ii >> 5);
    const int n0  = (ii & 31) * 64;
    const int b   = bh / NH;

    const float DN = 0.42044820762685725f;

    const float* Qh = Qg + (size_t)bh * NS * PD;
    const float* Kh = Kg + (size_t)bh * NS * PD;
    const float* Vh = Vg + (size_t)bh * NS * PD;
    const float* mk = maskg + (size_t)b * NS;

    {
        float sm = 0.f;
        for (int i = t; i < NS; i += 256) sm += mk[i];
        #pragma unroll
        for (int m = 1; m < 64; m <<= 1) sm += __shfl_xor(sm, m);
        if (lane == 0) red[w] = sm;
    }

    #pragma unroll
    for (int j = 0; j < 4; ++j) {
        const int idx = j * 256 + t;
        const int row = idx >> 4;
        const int u   = idx & 15;
        const float qs = mk[n0 + row] * DN;
        float4 v = *(const float4*)(Qh + (size_t)(n0 + row) * PD + 4 * u);
        v.x *= qs; v.y *= qs; v.z *= qs; v.w *= qs;
        uint2 h4, l4; split4(v, h4, l4);
        const int iu = (row * 64 + 4 * u) ^ ((row & 7) << 3);
        *(uint2*)&sQh[iu] = h4;
        *(uint2*)&sQl[iu] = l4;
        float d = dot4(v);
        d += __shfl_xor(d, 1); d += __shfl_xor(d, 2);
        d += __shfl_xor(d, 4); d += __shfl_xor(d, 8);
        if (u == 0) sdQ[row] = 0.5f * d;
    }
    __syncthreads();

    const float npn  = red[0] + red[1] + red[2] + red[3];
    const float vscl = DN / npn;

    s16x8 qbh[4], qbl[4];
    #pragma unroll
    for (int ks = 0; ks < 4; ++ks) {
        const int kc = 16 * ks + 8 * h;
        qbh[ks] = ldfrag(sQh, 32 * wq + c, kc);
        qbl[ks] = ldfrag(sQl, 32 * wq + c, kc);
    }
    const float dq = sdQ[32 * wq + c];

    f32x16 xacc[2];
    #pragma unroll
    for (int pt = 0; pt < 2; ++pt)
        #pragma unroll
        for (int r = 0; r < 16; ++r) xacc[pt][r] = 0.f;

    for (int mt = 0; mt < NS / 64; ++mt) {
        const int m0 = mt * 64;

        #pragma unroll
        for (int j = 0; j < 4; ++j) {
            const int idx = j * 256 + t;
            const int row = idx >> 4;
            const int u   = idx & 15;
            const float mr  = mk[m0 + row];
            const float ksc = mr * DN;
            float4 v = *(const float4*)(Kh + (size_t)(m0 + row) * PD + 4 * u);
            v.x *= ksc; v.y *= ksc; v.z *= ksc; v.w *= ksc;
            uint2 h4, l4; split4(v, h4, l4);
            const int iu = (row * 64 + 4 * u) ^ ((row & 7) << 3);
            *(uint2*)&sKh[iu] = h4;
            *(uint2*)&sKl[iu] = l4;
            float d = dot4(v);
            d += __shfl_xor(d, 1); d += __shfl_xor(d, 2);
            d += __shfl_xor(d, 4); d += __shfl_xor(d, 8);
            if (u == 0) scb[row] = fmaf(-1.0e9f, 1.f - mr, -0.5f * d);
        }
        #pragma unroll
        for (int j = 0; j < 4; ++j) {
            const int p  = lane;
            const int mq = 4 * j + ((w + (p >> 3)) & 3);
            const float* vc = Vh + (size_t)(m0 + 4 * mq) * PD + p;
            float4 mr = *(const float4*)&mk[m0 + 4 * mq];
            float4 v = make_float4(vc[0] * (mr.x * vscl), vc[PD] * (mr.y * vscl),
                                   vc[2 * PD] * (mr.z * vscl), vc[3 * PD] * (mr.w * vscl));
            *(uint2*)&sVt[(p * 64 + 4 * mq) ^ ((p & 7) << 3)] = cvt4h(v);
        }
        __syncthreads();

        f32x16 acc;
        #pragma unroll
        for (int r = 0; r < 16; ++r) acc[r] = 0.f;

        __builtin_amdgcn_s_setprio(1);
        #pragma unroll
        for (int ks = 0; ks < 4; ++ks) {
            const int kc = 16 * ks + 8 * h;
            const s16x8 kh = ldfrag(sKh, 32 * wm + c, kc);
            const s16x8 kl = ldfrag(sKl, 32 * wm + c, kc);
            acc = MFMAB(kh, qbh[ks], acc);
            acc = MFMAB(kh, qbl[ks], acc);
            acc = MFMAB(kl, qbh[ks], acc);
        }
        __builtin_amdgcn_s_setprio(0);

        float pv[16];
        #pragma unroll
        for (int g = 0; g < 4; ++g) {
            const f32x4 cb4 = *(const f32x4*)&scb[32 * wm + 8 * g + 4 * h];
            #pragma unroll
            for (int e = 0; e < 4; ++e)
                pv[4 * g + e] = __expf(acc[4 * g + e] - dq + cb4[e]);
        }

        #pragma unroll
        for (int ks2 = 0; ks2 < 2; ++ks2) {
            const int bb = 8 * ks2;
            unsigned w0 = pk2(pv[bb + 0], pv[bb + 1]);
            unsigned w1 = pk2(pv[bb + 2], pv[bb + 3]);
            unsigned w2 = pk2(pv[bb + 4], pv[bb + 5]);
            unsigned w3 = pk2(pv[bb + 6], pv[bb + 7]);
            pswap(w0, w2);
            pswap(w1, w3);
            union { unsigned int u[4]; s16x8 v; } pa;
            pa.u[0] = w0; pa.u[1] = w1; pa.u[2] = w2; pa.u[3] = w3;
            const int kc = 32 * wm + 16 * ks2 + 8 * h;
            __builtin_amdgcn_s_setprio(1);
            #pragma unroll
            for (int pt = 0; pt < 2; ++pt) {
                const s16x8 vb = ldfrag(sVt, 32 * pt + c, kc);
                xacc[pt] = MFMAB(pa.v, vb, xacc[pt]);
            }
            __builtin_amdgcn_s_setprio(0);
        }
        __syncthreads();
    }

    float* sX = (float*)sU;
    if (wm == 0) {
        #pragma unroll
        for (int pt = 0; pt < 2; ++pt)
            #pragma unroll
            for (int r = 0; r < 16; ++r) {
                const int row = 32 * wq + (r & 3) + 8 * (r >> 2) + 4 * h;
                sX[row * 64 + 32 * pt + c] = xacc[pt][r];
            }
    }
    __syncthreads();
    if (wm == 1) {
        float* Xh = Xg + (size_t)bh * NS * PD;
        #pragma unroll
        for (int pt = 0; pt < 2; ++pt)
            #pragma unroll
            for (int r = 0; r < 16; ++r) {
                const int row = 32 * wq + (r & 3) + 8 * (r >> 2) + 4 * h;
                const int col = 32 * pt + c;
                Xh[(size_t)(n0 + row) * PD + col] = sX[row * 64 + col] + xacc[pt][r];
            }
    }
}

extern "C" void kernel_launch(void* const* d_in, const int* in_sizes, int n_in,
                              void* d_out, int out_size, void* d_ws, size_t ws_size,
                              hipStream_t stream) {
    const float* Q    = (const float*)d_in[0];
    const float* K    = (const float*)d_in[1];
    const float* V    = (const float*)d_in[2];
    const float* mask = (const float*)d_in[3];
    float* X = (float*)d_out;

    const size_t need = (size_t)NB * NH * 32 * CHUNK;   // 25.6 MB
    if (d_ws != nullptr && ws_size >= need) {
        kde_pre<<<dim3(NB * NH * 32), dim3(256), 0, stream>>>(K, V, mask, (unsigned char*)d_ws);
        kde_main<<<dim3(NB * NH * 32), dim3(256), 0, stream>>>(Q, mask, (const unsigned char*)d_ws, X);
    } else {
        kde_attn_fb<<<dim3(NB * NH * 32), dim3(256), 0, stream>>>(Q, K, V, mask, X);
    }
}

// Round 14
// 97.482 us; speedup vs baseline: 1.0657x; 1.0657x over previous
//
#include <hip/hip_runtime.h>
#include <hip/hip_bf16.h>

#define NB 4
#define NH 12
#define NS 2048
#define PD 64
#define CHUNK 16640   // Kf16 frag-major 8192 + Vt f16 frag-major 8192 + cb' 256
#define LOG2E 1.4426950408889634f

typedef float f32x4  __attribute__((ext_vector_type(4)));
typedef float f32x16 __attribute__((ext_vector_type(16)));
typedef short s16x8  __attribute__((ext_vector_type(8)));
typedef _Float16 h16x8 __attribute__((ext_vector_type(8)));
typedef __fp16 fp16x2 __attribute__((ext_vector_type(2)));
typedef unsigned int u32x2 __attribute__((ext_vector_type(2)));

#define MFMAH(a, b, c) __builtin_amdgcn_mfma_f32_32x32x16_f16((a), (b), (c), 0, 0, 0)
#define MFMAB(a, b, c) __builtin_amdgcn_mfma_f32_32x32x16_bf16((a), (b), (c), 0, 0, 0)

typedef const __attribute__((address_space(1))) unsigned int* gas_t;
typedef __attribute__((address_space(3))) unsigned int* las_t;

static __device__ __forceinline__ unsigned short bfbits(float x) {
    __hip_bfloat16 h = __float2bfloat16(x);
    union { __hip_bfloat16 b; unsigned short u; } c; c.b = h; return c.u;
}
static __device__ __forceinline__ float bf2f(unsigned short u) {
    union { unsigned int i; float f; } c; c.i = ((unsigned int)u) << 16; return c.f;
}
static __device__ __forceinline__ unsigned short hbits(float x) {
    union { _Float16 h; unsigned short u; } c; c.h = (_Float16)x; return c.u;
}
static __device__ __forceinline__ float dot4(const float4& a) {
    return fmaf(a.x, a.x, fmaf(a.y, a.y, fmaf(a.z, a.z, a.w * a.w)));
}
static __device__ __forceinline__ uint2 cvt4f16(float4 v) {
    uint2 r;
    r.x = (unsigned)hbits(v.x) | ((unsigned)hbits(v.y) << 16);
    r.y = (unsigned)hbits(v.z) | ((unsigned)hbits(v.w) << 16);
    return r;
}
static __device__ __forceinline__ uint2 cvt4h(float4 v) {
    uint2 h4;
    h4.x = (unsigned)bfbits(v.x) | ((unsigned)bfbits(v.y) << 16);
    h4.y = (unsigned)bfbits(v.z) | ((unsigned)bfbits(v.w) << 16);
    return h4;
}
static __device__ __forceinline__ void split4(float4 v, uint2& h4, uint2& l4) {
    unsigned short h0 = bfbits(v.x), h1 = bfbits(v.y), h2 = bfbits(v.z), h3 = bfbits(v.w);
    unsigned short l0 = bfbits(v.x - bf2f(h0)), l1 = bfbits(v.y - bf2f(h1));
    unsigned short l2 = bfbits(v.z - bf2f(h2)), l3 = bfbits(v.w - bf2f(h3));
    h4.x = (unsigned)h0 | ((unsigned)h1 << 16); h4.y = (unsigned)h2 | ((unsigned)h3 << 16);
    l4.x = (unsigned)l0 | ((unsigned)l1 << 16); l4.y = (unsigned)l2 | ((unsigned)l3 << 16);
}
static __device__ __forceinline__ unsigned int pk2(float a, float b) {
    return (unsigned)bfbits(a) | ((unsigned)bfbits(b) << 16);
}
static __device__ __forceinline__ unsigned int pk2h(float a, float b) {
#if __has_builtin(__builtin_amdgcn_cvt_pkrtz)
    union { fp16x2 h; unsigned u; } c;
    c.h = __builtin_amdgcn_cvt_pkrtz(a, b);
    return c.u;
#else
    return (unsigned)hbits(a) | ((unsigned)hbits(b) << 16);
#endif
}
static __device__ __forceinline__ float fexp2(float x) {
#if __has_builtin(__builtin_amdgcn_exp2f)
    return __builtin_amdgcn_exp2f(x);
#else
    return exp2f(x);
#endif
}
// frag-major LDS read: [g][row(64)][8 ushort] — lanes hit consecutive 16B blocks
static __device__ __forceinline__ h16x8 ldfm(const unsigned short* base, int g, int row) {
    return *(const h16x8*)&base[(g * 64 + row) * 8];
}
// legacy swizzled read (fallback kernel)
static __device__ __forceinline__ s16x8 ldfrag(const unsigned short* s, int row, int kc) {
    return *(const s16x8*)&s[(row * 64 + kc) ^ ((row & 7) << 3)];
}
static __device__ __forceinline__ void pswap(unsigned int& a, unsigned int& b) {
#if __has_builtin(__builtin_amdgcn_permlane32_swap)
    u32x2 r = __builtin_amdgcn_permlane32_swap(a, b, false, false);
    a = r[0]; b = r[1];
#else
    const unsigned ax = (unsigned)__shfl_xor((int)a, 32);
    const unsigned bx = (unsigned)__shfl_xor((int)b, 32);
    const bool hi = (threadIdx.x & 32) != 0;
    const unsigned na = hi ? bx : a;
    const unsigned nb = hi ? b : ax;
    a = na; b = nb;
#endif
}
static __device__ __forceinline__ void gld16(const void* g, void* l) {
#if __has_builtin(__builtin_amdgcn_global_load_lds)
    __builtin_amdgcn_global_load_lds((gas_t)g, (las_t)l, 16, 0, 0);
#else
    ((uint4*)l)[threadIdx.x & 63] = *(const uint4*)g;
#endif
}
static __device__ __forceinline__ void gld4(const void* g, void* l) {
#if __has_builtin(__builtin_amdgcn_global_load_lds)
    __builtin_amdgcn_global_load_lds((gas_t)g, (las_t)l, 4, 0, 0);
#else
    ((float*)l)[threadIdx.x & 63] = *(const float*)g;
#endif
}

// ---------------- precompute: frag-major f16 K(xlog2e)/Vt + cb' chunks (unchanged) ----------------
__global__ __launch_bounds__(256, 4) void kde_pre(
    const float* __restrict__ Kg, const float* __restrict__ Vg,
    const float* __restrict__ maskg, unsigned char* __restrict__ ws)
{
    const int t    = threadIdx.x;
    const int lane = t & 63;
    const int w    = t >> 6;

    const int s   = blockIdx.x;
    const int xcd = s & 7;
    const int ii  = s >> 3;
    const int bh  = 6 * xcd + (ii >> 5);
    const int mt  = ii & 31;
    const int b   = bh / NH;
    const int m0  = mt * 64;

    const float DN = 0.42044820762685725f;

    const float* Kh = Kg + (size_t)bh * NS * PD;
    const float* Vh = Vg + (size_t)bh * NS * PD;
    const float* mk = maskg + (size_t)b * NS;

    unsigned char* ch = ws + (size_t)(bh * 32 + mt) * CHUNK;
    unsigned short* gK  = (unsigned short*)ch;
    unsigned short* gVt = gK + 4096;
    float* gcb = (float*)(ch + 16384);

    #pragma unroll
    for (int j = 0; j < 4; ++j) {
        const int idx = j * 256 + t;
        const int row = idx >> 4;
        const int u   = idx & 15;
        const float mr  = mk[m0 + row];
        const float ksc = mr * DN;
        float4 v = *(const float4*)(Kh + (size_t)(m0 + row) * PD + 4 * u);
        v.x *= ksc; v.y *= ksc; v.z *= ksc; v.w *= ksc;
        float d = dot4(v);
        float4 vl = make_float4(v.x * LOG2E, v.y * LOG2E, v.z * LOG2E, v.w * LOG2E);
        *(uint2*)&gK[((u >> 1) * 64 + row) * 8 + 4 * (u & 1)] = cvt4f16(vl);
        d += __shfl_xor(d, 1); d += __shfl_xor(d, 2);
        d += __shfl_xor(d, 4); d += __shfl_xor(d, 8);
        if (u == 0) gcb[row] = fmaf(-1.0e9f, 1.f - mr, -0.5f * d) * LOG2E;
    }
    #pragma unroll
    for (int j = 0; j < 4; ++j) {
        const int p  = lane;
        const int mq = 4 * j + ((w + (p >> 3)) & 3);
        const float* vc = Vh + (size_t)(m0 + 4 * mq) * PD + p;
        float4 mr = *(const float4*)&mk[m0 + 4 * mq];
        float4 v = make_float4(vc[0] * (mr.x * DN), vc[PD] * (mr.y * DN),
                               vc[2 * PD] * (mr.z * DN), vc[3 * PD] * (mr.w * DN));
        *(uint2*)&gVt[((mq >> 1) * 64 + p) * 8 + 4 * (mq & 1)] = cvt4f16(v);
    }
}

// ---------------- main: triple-buffer, ONE barrier/mt, cb as MFMA C-in ----------------
__global__ __launch_bounds__(256) void kde_main(
    const float* __restrict__ Qg, const float* __restrict__ maskg,
    const unsigned char* __restrict__ ws, float* __restrict__ Xg)
{
    __shared__ __align__(16) unsigned short sT[3][8320];   // 3 x (K|Vt|cb) images
    __shared__ float sdQ[64], red[4];

    unsigned short* const sQ  = &sT[0][0];       // prologue alias (8 KB)
    float* const sXf          = (float*)&sT[0][0];  // epilogue alias (16 KB)

    const int t    = threadIdx.x;
    const int lane = t & 63;
    const int w    = t >> 6;
    const int h    = lane >> 5;
    const int c    = lane & 31;
    const int wm   = w >> 1;
    const int wq   = w & 1;

    // XCD-bijective remap: 1536 blocks = 8 XCD * (6 bh * 32 qb)
    const int s   = blockIdx.x;
    const int xcd = s & 7;
    const int ii  = s >> 3;
    const int bh  = 6 * xcd + (ii >> 5);
    const int n0  = (ii & 31) * 64;
    const int b   = bh / NH;

    const float DN = 0.42044820762685725f;

    const float* Qh = Qg + (size_t)bh * NS * PD;
    const float* mk = maskg + (size_t)b * NS;
    const unsigned char* chb = ws + (size_t)bh * 32 * CHUNK;

    // ---- npn ----
    {
        float sm = 0.f;
        for (int i = t; i < NS; i += 256) sm += mk[i];
        #pragma unroll
        for (int m = 1; m < 64; m <<= 1) sm += __shfl_xor(sm, m);
        if (lane == 0) red[w] = sm;
    }

    // ---- stage Q (scaled, f16, frag-major) + diag_Q ----
    #pragma unroll
    for (int j = 0; j < 4; ++j) {
        const int idx = j * 256 + t;
        const int row = idx >> 4;
        const int u   = idx & 15;
        const float qs = mk[n0 + row] * DN;
        float4 v = *(const float4*)(Qh + (size_t)(n0 + row) * PD + 4 * u);
        v.x *= qs; v.y *= qs; v.z *= qs; v.w *= qs;
        *(uint2*)&sQ[((u >> 1) * 64 + row) * 8 + 4 * (u & 1)] = cvt4f16(v);
        float d = dot4(v);
        d += __shfl_xor(d, 1); d += __shfl_xor(d, 2);
        d += __shfl_xor(d, 4); d += __shfl_xor(d, 8);
        if (u == 0) sdQ[row] = 0.5f * d;
    }
    __syncthreads();

    const float npn  = red[0] + red[1] + red[2] + red[3];
    const float invn = 1.f / npn;

    // ---- hoist Q B-fragments (4 x b128 = 16 VGPR) ----
    h16x8 qb[4];
    #pragma unroll
    for (int ks = 0; ks < 4; ++ks)
        qb[ks] = ldfm(sQ, 2 * ks + h, 32 * wq + c);
    __syncthreads();   // sT free for chunk staging

    f32x16 xacc[2];
    #pragma unroll
    for (int pt = 0; pt < 2; ++pt)
        #pragma unroll
        for (int r = 0; r < 16; ++r) xacc[pt][r] = 0.f;

#define STAGE(BASE, MT) do {                                             \
        const unsigned char* chp_ = chb + (size_t)(MT) * CHUNK;          \
        unsigned char* lb_ = (unsigned char*)(BASE);                     \
        _Pragma("unroll")                                                \
        for (int j_ = 0; j_ < 4; ++j_) {                                 \
            const int seg_ = 4 * w + j_;                                 \
            gld16(chp_ + seg_ * 1024 + 16 * lane, lb_ + seg_ * 1024);    \
        }                                                                \
        gld4(chp_ + 16384 + 4 * lane, lb_ + 16384);                      \
    } while (0)

    unsigned short* bufA = &sT[0][0];
    unsigned short* bufB = &sT[1][0];
    unsigned short* bufC = &sT[2][0];

    STAGE(bufA, 0);

    for (int mt = 0; mt < 32; ++mt) {
        if (mt + 1 < 32) {
            STAGE(bufB, mt + 1);
            asm volatile("s_waitcnt vmcnt(5)" ::: "memory");   // tile mt landed; mt+1 in flight
        } else {
            asm volatile("s_waitcnt vmcnt(0)" ::: "memory");
        }
        __builtin_amdgcn_s_barrier();
        __builtin_amdgcn_sched_barrier(0);

        const unsigned short* bK  = bufA;
        const unsigned short* bVt = bufA + 4096;
        const float* bcb = (const float*)(bufA + 8192);

        // ---- acc C-in = cb' (dq folded to epilogue) ----
        f32x16 acc;
        #pragma unroll
        for (int g4 = 0; g4 < 4; ++g4) {
            const f32x4 cb4 = *(const f32x4*)&bcb[32 * wm + 8 * g4 + 4 * h];
            #pragma unroll
            for (int e = 0; e < 4; ++e)
                acc[4 * g4 + e] = cb4[e];
        }

        // ---- S' = Ks~ . Qs^T + cb' ----
        __builtin_amdgcn_s_setprio(1);
        #pragma unroll
        for (int ks = 0; ks < 4; ++ks) {
            const h16x8 kh = ldfm(bK, 2 * ks + h, 32 * wm + c);
            acc = MFMAH(kh, qb[ks], acc);
        }
        __builtin_amdgcn_s_setprio(0);

        // ---- P~ = exp2(acc) in-register ----
        float pv[16];
        #pragma unroll
        for (int r = 0; r < 16; ++r)
            pv[r] = fexp2(acc[r]);

        // ---- X_partial += P~^T . V ----
        #pragma unroll
        for (int ks2 = 0; ks2 < 2; ++ks2) {
            const int bb = 8 * ks2;
            unsigned a0 = pk2h(pv[bb + 0], pv[bb + 1]);
            unsigned a1 = pk2h(pv[bb + 2], pv[bb + 3]);
            unsigned a2 = pk2h(pv[bb + 4], pv[bb + 5]);
            unsigned a3 = pk2h(pv[bb + 6], pv[bb + 7]);
            pswap(a0, a2); pswap(a1, a3);
            union { unsigned int u[4]; h16x8 v; } pa;
            pa.u[0] = a0; pa.u[1] = a1; pa.u[2] = a2; pa.u[3] = a3;
            const int gv = 4 * wm + 2 * ks2 + h;
            __builtin_amdgcn_s_setprio(1);
            const h16x8 vb0 = ldfm(bVt, gv, c);
            const h16x8 vb1 = ldfm(bVt, gv, 32 + c);
            xacc[0] = MFMAH(pa.v, vb0, xacc[0]);
            xacc[1] = MFMAH(pa.v, vb1, xacc[1]);
            __builtin_amdgcn_s_setprio(0);
        }

        // rotate buffers: computed A retires, staged B becomes next compute
        unsigned short* tmp = bufA; bufA = bufB; bufB = bufC; bufC = tmp;
        // NO end-of-iter barrier: 3rd buffer guarantees no WAR across waves
    }
#undef STAGE

    __syncthreads();   // all compute done before epilogue aliases sT

    // ---- cross-wave (wm) reduction via LDS; scale exp2(-dq')*invn; write X ----
    if (wm == 0) {
        #pragma unroll
        for (int pt = 0; pt < 2; ++pt)
            #pragma unroll
            for (int r = 0; r < 16; ++r) {
                const int row = 32 * wq + (r & 3) + 8 * (r >> 2) + 4 * h;
                sXf[row * 64 + 32 * pt + c] = xacc[pt][r];
            }
    }
    __syncthreads();
    if (wm == 1) {
        float* Xh = Xg + (size_t)bh * NS * PD;
        #pragma unroll
        for (int pt = 0; pt < 2; ++pt)
            #pragma unroll
            for (int r = 0; r < 16; ++r) {
                const int row = 32 * wq + (r & 3) + 8 * (r >> 2) + 4 * h;
                const int col = 32 * pt + c;
                const float sc = fexp2(-sdQ[row] * LOG2E) * invn;
                Xh[(size_t)(n0 + row) * PD + col] = (sXf[row * 64 + col] + xacc[pt][r]) * sc;
            }
    }
}

// ---------------- fallback (R6 kernel, bf16 split) if ws too small ----------------
__global__ __launch_bounds__(256, 2) void kde_attn_fb(
    const float* __restrict__ Qg, const float* __restrict__ Kg,
    const float* __restrict__ Vg, const float* __restrict__ maskg,
    float* __restrict__ Xg)
{
    __shared__ __align__(16) unsigned short sKh[4096], sKl[4096], sVt[4096];
    __shared__ __align__(16) unsigned short sU[8192];
    __shared__ __align__(16) float scb[64];
    __shared__ float sdQ[64], red[4];

    unsigned short* const sQh = sU;
    unsigned short* const sQl = sU + 4096;

    const int t    = threadIdx.x;
    const int lane = t & 63;
    const int w    = t >> 6;
    const int h    = lane >> 5;
    const int c    = lane & 31;
    const int wm   = w >> 1;
    const int wq   = w & 1;

    const int s   = blockIdx.x;
    const int xcd = s & 7;
    const int ii  = s >> 3;
    const int bh  = 6 * xcd + (ii >> 5);
    const int n0  = (ii & 31) * 64;
    const int b   = bh / NH;

    const float DN = 0.42044820762685725f;

    const float* Qh = Qg + (size_t)bh * NS * PD;
    const float* Kh = Kg + (size_t)bh * NS * PD;
    const float* Vh = Vg + (size_t)bh * NS * PD;
    const float* mk = maskg + (size_t)b * NS;

    {
        float sm = 0.f;
        for (int i = t; i < NS; i += 256) sm += mk[i];
        #pragma unroll
        for (int m = 1; m < 64; m <<= 1) sm += __shfl_xor(sm, m);
        if (lane == 0) red[w] = sm;
    }

    #pragma unroll
    for (int j = 0; j < 4; ++j) {
        const int idx = j * 256 + t;
        const int row = idx >> 4;
        const int u   = idx & 15;
        const float qs = mk[n0 + row] * DN;
        float4 v = *(const float4*)(Qh + (size_t)(n0 + row) * PD + 4 * u);
        v.x *= qs; v.y *= qs; v.z *= qs; v.w *= qs;
        uint2 h4, l4; split4(v, h4, l4);
        const int iu = (row * 64 + 4 * u) ^ ((row & 7) << 3);
        *(uint2*)&sQh[iu] = h4;
        *(uint2*)&sQl[iu] = l4;
        float d = dot4(v);
        d += __shfl_xor(d, 1); d += __shfl_xor(d, 2);
        d += __shfl_xor(d, 4); d += __shfl_xor(d, 8);
        if (u == 0) sdQ[row] = 0.5f * d;
    }
    __syncthreads();

    const float npn  = red[0] + red[1] + red[2] + red[3];
    const float vscl = DN / npn;

    s16x8 qbh[4], qbl[4];
    #pragma unroll
    for (int ks = 0; ks < 4; ++ks) {
        const int kc = 16 * ks + 8 * h;
        qbh[ks] = ldfrag(sQh, 32 * wq + c, kc);
        qbl[ks] = ldfrag(sQl, 32 * wq + c, kc);
    }
    const float dq = sdQ[32 * wq + c];

    f32x16 xacc[2];
    #pragma unroll
    for (int pt = 0; pt < 2; ++pt)
        #pragma unroll
        for (int r = 0; r < 16; ++r) xacc[pt][r] = 0.f;

    for (int mt = 0; mt < NS / 64; ++mt) {
        const int m0 = mt * 64;

        #pragma unroll
        for (int j = 0; j < 4; ++j) {
            const int idx = j * 256 + t;
            const int row = idx >> 4;
            const int u   = idx & 15;
            const float mr  = mk[m0 + row];
            const float ksc = mr * DN;
            float4 v = *(const float4*)(Kh + (size_t)(m0 + row) * PD + 4 * u);
            v.x *= ksc; v.y *= ksc; v.z *= ksc; v.w *= ksc;
            uint2 h4, l4; split4(v, h4, l4);
            const int iu = (row * 64 + 4 * u) ^ ((row & 7) << 3);
            *(uint2*)&sKh[iu] = h4;
            *(uint2*)&sKl[iu] = l4;
            float d = dot4(v);
            d += __shfl_xor(d, 1); d += __shfl_xor(d, 2);
            d += __shfl_xor(d, 4); d += __shfl_xor(d, 8);
            if (u == 0) scb[row] = fmaf(-1.0e9f, 1.f - mr, -0.5f * d);
        }
        #pragma unroll
        for (int j = 0; j < 4; ++j) {
            const int p  = lane;
            const int mq = 4 * j + ((w + (p >> 3)) & 3);
            const float* vc = Vh + (size_t)(m0 + 4 * mq) * PD + p;
            float4 mr = *(const float4*)&mk[m0 + 4 * mq];
            float4 v = make_float4(vc[0] * (mr.x * vscl), vc[PD] * (mr.y * vscl),
                                   vc[2 * PD] * (mr.z * vscl), vc[3 * PD] * (mr.w * vscl));
            *(uint2*)&sVt[(p * 64 + 4 * mq) ^ ((p & 7) << 3)] = cvt4h(v);
        }
        __syncthreads();

        f32x16 acc;
        #pragma unroll
        for (int r = 0; r < 16; ++r) acc[r] = 0.f;

        __builtin_amdgcn_s_setprio(1);
        #pragma unroll
        for (int ks = 0; ks < 4; ++ks) {
            const int kc = 16 * ks + 8 * h;
            const s16x8 kh = ldfrag(sKh, 32 * wm + c, kc);
            const s16x8 kl = ldfrag(sKl, 32 * wm + c, kc);
            acc = MFMAB(kh, qbh[ks], acc);
            acc = MFMAB(kh, qbl[ks], acc);
            acc = MFMAB(kl, qbh[ks], acc);
        }
        __builtin_amdgcn_s_setprio(0);

        float pv[16];
        #pragma unroll
        for (int g = 0; g < 4; ++g) {
            const f32x4 cb4 = *(const f32x4*)&scb[32 * wm + 8 * g + 4 * h];
            #pragma unroll
            for (int e = 0; e < 4; ++e)
                pv[4 * g + e] = __expf(acc[4 * g + e] - dq + cb4[e]);
        }

        #pragma unroll
        for (int ks2 = 0; ks2 < 2; ++ks2) {
            const int bb = 8 * ks2;
            unsigned w0 = pk2(pv[bb + 0], pv[bb + 1]);
            unsigned w1 = pk2(pv[bb + 2], pv[bb + 3]);
            unsigned w2 = pk2(pv[bb + 4], pv[bb + 5]);
            unsigned w3 = pk2(pv[bb + 6], pv[bb + 7]);
            pswap(w0, w2);
            pswap(w1, w3);
            union { unsigned int u[4]; s16x8 v; } pa;
            pa.u[0] = w0; pa.u[1] = w1; pa.u[2] = w2; pa.u[3] = w3;
            const int kc = 32 * wm + 16 * ks2 + 8 * h;
            __builtin_amdgcn_s_setprio(1);
            #pragma unroll
            for (int pt = 0; pt < 2; ++pt) {
                const s16x8 vb = ldfrag(sVt, 32 * pt + c, kc);
                xacc[pt] = MFMAB(pa.v, vb, xacc[pt]);
            }
            __builtin_amdgcn_s_setprio(0);
        }
        __syncthreads();
    }

    float* sX = (float*)sU;
    if (wm == 0) {
        #pragma unroll
        for (int pt = 0; pt < 2; ++pt)
            #pragma unroll
            for (int r = 0; r < 16; ++r) {
                const int row = 32 * wq + (r & 3) + 8 * (r >> 2) + 4 * h;
                sX[row * 64 + 32 * pt + c] = xacc[pt][r];
            }
    }
    __syncthreads();
    if (wm == 1) {
        float* Xh = Xg + (size_t)bh * NS * PD;
        #pragma unroll
        for (int pt = 0; pt < 2; ++pt)
            #pragma unroll
            for (int r = 0; r < 16; ++r) {
                const int row = 32 * wq + (r & 3) + 8 * (r >> 2) + 4 * h;
                const int col = 32 * pt + c;
                Xh[(size_t)(n0 + row) * PD + col] = sX[row * 64 + col] + xacc[pt][r];
            }
    }
}

extern "C" void kernel_launch(void* const* d_in, const int* in_sizes, int n_in,
                              void* d_out, int out_size, void* d_ws, size_t ws_size,
                              hipStream_t stream) {
    const float* Q    = (const float*)d_in[0];
    const float* K    = (const float*)d_in[1];
    const float* V    = (const float*)d_in[2];
    const float* mask = (const float*)d_in[3];
    float* X = (float*)d_out;

    const size_t need = (size_t)NB * NH * 32 * CHUNK;   // 25.6 MB
    if (d_ws != nullptr && ws_size >= need) {
        kde_pre<<<dim3(NB * NH * 32), dim3(256), 0, stream>>>(K, V, mask, (unsigned char*)d_ws);
        kde_main<<<dim3(NB * NH * 32), dim3(256), 0, stream>>>(Q, mask, (const unsigned char*)d_ws, X);
    } else {
        kde_attn_fb<<<dim3(NB * NH * 32), dim3(256), 0, stream>>>(Q, K, V, mask, X);
    }
}

// Round 15
// 82.497 us; speedup vs baseline: 1.2593x; 1.1816x over previous
//
#include <hip/hip_runtime.h>
#include <hip/hip_bf16.h>

#define NB 4
#define NH 12
#define NS 2048
#define PD 64
#define CHUNK 16640   // Kf16 frag-major 8192 + Vt f16 frag-major 8192 + cb' 256
#define LOG2E 1.4426950408889634f

typedef float f32x4  __attribute__((ext_vector_type(4)));
typedef float f32x16 __attribute__((ext_vector_type(16)));
typedef short s16x8  __attribute__((ext_vector_type(8)));
typedef _Float16 h16x8 __attribute__((ext_vector_type(8)));
typedef __fp16 fp16x2 __attribute__((ext_vector_type(2)));
typedef unsigned int u32x2 __attribute__((ext_vector_type(2)));

#define MFMAH(a, b, c) __builtin_amdgcn_mfma_f32_32x32x16_f16((a), (b), (c), 0, 0, 0)
#define MFMAB(a, b, c) __builtin_amdgcn_mfma_f32_32x32x16_bf16((a), (b), (c), 0, 0, 0)

typedef const __attribute__((address_space(1))) unsigned int* gas_t;
typedef __attribute__((address_space(3))) unsigned int* las_t;

static __device__ __forceinline__ unsigned short bfbits(float x) {
    __hip_bfloat16 h = __float2bfloat16(x);
    union { __hip_bfloat16 b; unsigned short u; } c; c.b = h; return c.u;
}
static __device__ __forceinline__ float bf2f(unsigned short u) {
    union { unsigned int i; float f; } c; c.i = ((unsigned int)u) << 16; return c.f;
}
static __device__ __forceinline__ unsigned short hbits(float x) {
    union { _Float16 h; unsigned short u; } c; c.h = (_Float16)x; return c.u;
}
static __device__ __forceinline__ float dot4(const float4& a) {
    return fmaf(a.x, a.x, fmaf(a.y, a.y, fmaf(a.z, a.z, a.w * a.w)));
}
static __device__ __forceinline__ uint2 cvt4f16(float4 v) {
    uint2 r;
    r.x = (unsigned)hbits(v.x) | ((unsigned)hbits(v.y) << 16);
    r.y = (unsigned)hbits(v.z) | ((unsigned)hbits(v.w) << 16);
    return r;
}
static __device__ __forceinline__ uint2 cvt4h(float4 v) {
    uint2 h4;
    h4.x = (unsigned)bfbits(v.x) | ((unsigned)bfbits(v.y) << 16);
    h4.y = (unsigned)bfbits(v.z) | ((unsigned)bfbits(v.w) << 16);
    return h4;
}
static __device__ __forceinline__ void split4(float4 v, uint2& h4, uint2& l4) {
    unsigned short h0 = bfbits(v.x), h1 = bfbits(v.y), h2 = bfbits(v.z), h3 = bfbits(v.w);
    unsigned short l0 = bfbits(v.x - bf2f(h0)), l1 = bfbits(v.y - bf2f(h1));
    unsigned short l2 = bfbits(v.z - bf2f(h2)), l3 = bfbits(v.w - bf2f(h3));
    h4.x = (unsigned)h0 | ((unsigned)h1 << 16); h4.y = (unsigned)h2 | ((unsigned)h3 << 16);
    l4.x = (unsigned)l0 | ((unsigned)l1 << 16); l4.y = (unsigned)l2 | ((unsigned)l3 << 16);
}
static __device__ __forceinline__ unsigned int pk2(float a, float b) {
    return (unsigned)bfbits(a) | ((unsigned)bfbits(b) << 16);
}
static __device__ __forceinline__ unsigned int pk2h(float a, float b) {
#if __has_builtin(__builtin_amdgcn_cvt_pkrtz)
    union { fp16x2 h; unsigned u; } c;
    c.h = __builtin_amdgcn_cvt_pkrtz(a, b);
    return c.u;
#else
    return (unsigned)hbits(a) | ((unsigned)hbits(b) << 16);
#endif
}
static __device__ __forceinline__ float fexp2(float x) {
#if __has_builtin(__builtin_amdgcn_exp2f)
    return __builtin_amdgcn_exp2f(x);
#else
    return exp2f(x);
#endif
}
// frag-major LDS read, stride 64 rows (K/V chunks): [g][64][8]
static __device__ __forceinline__ h16x8 ldfm(const unsigned short* base, int g, int row) {
    return *(const h16x8*)&base[(g * 64 + row) * 8];
}
// frag-major LDS read, stride 128 rows (Q prologue): [g][128][8]
static __device__ __forceinline__ h16x8 ldfm128(const unsigned short* base, int g, int row) {
    return *(const h16x8*)&base[(g * 128 + row) * 8];
}
// legacy swizzled read (fallback kernel)
static __device__ __forceinline__ s16x8 ldfrag(const unsigned short* s, int row, int kc) {
    return *(const s16x8*)&s[(row * 64 + kc) ^ ((row & 7) << 3)];
}
static __device__ __forceinline__ void pswap(unsigned int& a, unsigned int& b) {
#if __has_builtin(__builtin_amdgcn_permlane32_swap)
    u32x2 r = __builtin_amdgcn_permlane32_swap(a, b, false, false);
    a = r[0]; b = r[1];
#else
    const unsigned ax = (unsigned)__shfl_xor((int)a, 32);
    const unsigned bx = (unsigned)__shfl_xor((int)b, 32);
    const bool hi = (threadIdx.x & 32) != 0;
    const unsigned na = hi ? bx : a;
    const unsigned nb = hi ? b : ax;
    a = na; b = nb;
#endif
}
static __device__ __forceinline__ void gld16(const void* g, void* l) {
#if __has_builtin(__builtin_amdgcn_global_load_lds)
    __builtin_amdgcn_global_load_lds((gas_t)g, (las_t)l, 16, 0, 0);
#else
    ((uint4*)l)[threadIdx.x & 63] = *(const uint4*)g;
#endif
}
static __device__ __forceinline__ void gld4(const void* g, void* l) {
#if __has_builtin(__builtin_amdgcn_global_load_lds)
    __builtin_amdgcn_global_load_lds((gas_t)g, (las_t)l, 4, 0, 0);
#else
    ((float*)l)[threadIdx.x & 63] = *(const float*)g;
#endif
}

// ---------------- precompute: frag-major f16 K(xlog2e)/Vt + cb' chunks (unchanged) ----------------
__global__ __launch_bounds__(256, 4) void kde_pre(
    const float* __restrict__ Kg, const float* __restrict__ Vg,
    const float* __restrict__ maskg, unsigned char* __restrict__ ws)
{
    const int t    = threadIdx.x;
    const int lane = t & 63;
    const int w    = t >> 6;

    const int s   = blockIdx.x;
    const int xcd = s & 7;
    const int ii  = s >> 3;
    const int bh  = 6 * xcd + (ii >> 5);
    const int mt  = ii & 31;
    const int b   = bh / NH;
    const int m0  = mt * 64;

    const float DN = 0.42044820762685725f;

    const float* Kh = Kg + (size_t)bh * NS * PD;
    const float* Vh = Vg + (size_t)bh * NS * PD;
    const float* mk = maskg + (size_t)b * NS;

    unsigned char* ch = ws + (size_t)(bh * 32 + mt) * CHUNK;
    unsigned short* gK  = (unsigned short*)ch;
    unsigned short* gVt = gK + 4096;
    float* gcb = (float*)(ch + 16384);

    #pragma unroll
    for (int j = 0; j < 4; ++j) {
        const int idx = j * 256 + t;
        const int row = idx >> 4;
        const int u   = idx & 15;
        const float mr  = mk[m0 + row];
        const float ksc = mr * DN;
        float4 v = *(const float4*)(Kh + (size_t)(m0 + row) * PD + 4 * u);
        v.x *= ksc; v.y *= ksc; v.z *= ksc; v.w *= ksc;
        float d = dot4(v);
        float4 vl = make_float4(v.x * LOG2E, v.y * LOG2E, v.z * LOG2E, v.w * LOG2E);
        *(uint2*)&gK[((u >> 1) * 64 + row) * 8 + 4 * (u & 1)] = cvt4f16(vl);
        d += __shfl_xor(d, 1); d += __shfl_xor(d, 2);
        d += __shfl_xor(d, 4); d += __shfl_xor(d, 8);
        if (u == 0) gcb[row] = fmaf(-1.0e9f, 1.f - mr, -0.5f * d) * LOG2E;
    }
    #pragma unroll
    for (int j = 0; j < 4; ++j) {
        const int p  = lane;
        const int mq = 4 * j + ((w + (p >> 3)) & 3);
        const float* vc = Vh + (size_t)(m0 + 4 * mq) * PD + p;
        float4 mr = *(const float4*)&mk[m0 + 4 * mq];
        float4 v = make_float4(vc[0] * (mr.x * DN), vc[PD] * (mr.y * DN),
                               vc[2 * PD] * (mr.z * DN), vc[3 * PD] * (mr.w * DN));
        *(uint2*)&gVt[((mq >> 1) * 64 + p) * 8 + 4 * (mq & 1)] = cvt4f16(v);
    }
}

// ---------------- main: 512 thr, 128-q block, 4-buffer depth-2 prefetch, 1 barrier/mt ----------------
__global__ __launch_bounds__(512) void kde_main(
    const float* __restrict__ Qg, const float* __restrict__ maskg,
    const unsigned char* __restrict__ ws, float* __restrict__ Xg)
{
    __shared__ __align__(16) unsigned short sT[4][8320];   // 4 x (K|Vt|cb) images, 66.6 KB
    __shared__ float sdQ[128], red[8];

    unsigned short* const sQ = &sT[0][0];        // prologue alias (16 KB, frag-major [g][128][8])
    float* const sXf         = (float*)&sT[0][0];   // epilogue alias (32 KB)

    const int t    = threadIdx.x;
    const int lane = t & 63;
    const int w    = t >> 6;      // 0..7
    const int h    = lane >> 5;
    const int c    = lane & 31;
    const int wm   = w & 1;       // m-half
    const int wq   = w >> 1;      // q-quarter of 128

    // XCD-bijective remap: 768 blocks = 8 XCD * (6 bh * 16 qb)
    const int s   = blockIdx.x;
    const int xcd = s & 7;
    const int ii  = s >> 3;
    const int bh  = 6 * xcd + (ii >> 4);
    const int n0  = (ii & 15) * 128;
    const int b   = bh / NH;

    const float DN = 0.42044820762685725f;

    const float* Qh = Qg + (size_t)bh * NS * PD;
    const float* mk = maskg + (size_t)b * NS;
    const unsigned char* chb = ws + (size_t)bh * 32 * CHUNK;

    // ---- npn ----
    {
        float sm = 0.f;
        for (int i = t; i < NS; i += 512) sm += mk[i];
        #pragma unroll
        for (int m = 1; m < 64; m <<= 1) sm += __shfl_xor(sm, m);
        if (lane == 0) red[w] = sm;
    }

    // ---- stage Q (128 rows, scaled, f16, frag-major stride-128) + diag_Q ----
    #pragma unroll
    for (int j = 0; j < 4; ++j) {
        const int idx = j * 512 + t;
        const int row = idx >> 4;     // 0..127
        const int u   = idx & 15;
        const float qs = mk[n0 + row] * DN;
        float4 v = *(const float4*)(Qh + (size_t)(n0 + row) * PD + 4 * u);
        v.x *= qs; v.y *= qs; v.z *= qs; v.w *= qs;
        *(uint2*)&sQ[((u >> 1) * 128 + row) * 8 + 4 * (u & 1)] = cvt4f16(v);
        float d = dot4(v);
        d += __shfl_xor(d, 1); d += __shfl_xor(d, 2);
        d += __shfl_xor(d, 4); d += __shfl_xor(d, 8);
        if (u == 0) sdQ[row] = 0.5f * d;
    }
    __syncthreads();

    const float npn = red[0] + red[1] + red[2] + red[3] +
                      red[4] + red[5] + red[6] + red[7];
    const float invn = 1.f / npn;

    // ---- hoist Q B-fragments (4 x b128 = 16 VGPR) ----
    h16x8 qb[4];
    #pragma unroll
    for (int ks = 0; ks < 4; ++ks)
        qb[ks] = ldfm128(sQ, 2 * ks + h, 32 * wq + c);
    __syncthreads();   // sT free for chunk staging

    f32x16 xacc[2];
    #pragma unroll
    for (int pt = 0; pt < 2; ++pt)
        #pragma unroll
        for (int r = 0; r < 16; ++r) xacc[pt][r] = 0.f;

    // wave w stages segs {2w, 2w+1}; wave 0 additionally stages cb (L: w0=3, else 2)
#define STAGE(BASE, MT) do {                                             \
        const unsigned char* chp_ = chb + (size_t)(MT) * CHUNK;          \
        unsigned char* lb_ = (unsigned char*)(BASE);                     \
        _Pragma("unroll")                                                \
        for (int j_ = 0; j_ < 2; ++j_) {                                 \
            const int seg_ = 2 * w + j_;                                 \
            gld16(chp_ + seg_ * 1024 + 16 * lane, lb_ + seg_ * 1024);    \
        }                                                                \
        if (w == 0) gld4(chp_ + 16384 + 4 * lane, lb_ + 16384);          \
    } while (0)

    unsigned short* bufA = &sT[0][0];   // compute (tile mt)
    unsigned short* bufB = &sT[1][0];   // tile mt+1 (in flight/landed)
    unsigned short* bufC = &sT[2][0];   // retired (computed mt-1)
    unsigned short* bufD = &sT[3][0];   // stage target (retired mt-2)

    STAGE(bufA, 0);
    STAGE(bufB, 1);

    for (int mt = 0; mt < 32; ++mt) {
        if (mt < 30) {
            STAGE(bufD, mt + 2);
            // wait tile mt landed: outstanding <= loads(mt+1)+loads(mt+2) = 2L
            if (w == 0) { asm volatile("s_waitcnt vmcnt(6)" ::: "memory"); }
            else        { asm volatile("s_waitcnt vmcnt(4)" ::: "memory"); }
        } else if (mt == 30) {
            if (w == 0) { asm volatile("s_waitcnt vmcnt(3)" ::: "memory"); }
            else        { asm volatile("s_waitcnt vmcnt(2)" ::: "memory"); }
        } else {
            asm volatile("s_waitcnt vmcnt(0)" ::: "memory");
        }
        __builtin_amdgcn_s_barrier();
        __builtin_amdgcn_sched_barrier(0);

        const unsigned short* bK  = bufA;
        const unsigned short* bVt = bufA + 4096;
        const float* bcb = (const float*)(bufA + 8192);

        // ---- acc C-in = cb' (dq folded to epilogue) ----
        f32x16 acc;
        #pragma unroll
        for (int g4 = 0; g4 < 4; ++g4) {
            const f32x4 cb4 = *(const f32x4*)&bcb[32 * wm + 8 * g4 + 4 * h];
            #pragma unroll
            for (int e = 0; e < 4; ++e)
                acc[4 * g4 + e] = cb4[e];
        }

        // ---- S' = Ks~ . Qs^T + cb' ----
        __builtin_amdgcn_s_setprio(1);
        #pragma unroll
        for (int ks = 0; ks < 4; ++ks) {
            const h16x8 kh = ldfm(bK, 2 * ks + h, 32 * wm + c);
            acc = MFMAH(kh, qb[ks], acc);
        }
        __builtin_amdgcn_s_setprio(0);

        // ---- P~ = exp2(acc) ----
        float pv[16];
        #pragma unroll
        for (int r = 0; r < 16; ++r)
            pv[r] = fexp2(acc[r]);

        // ---- X_partial += P~^T . V ----
        #pragma unroll
        for (int ks2 = 0; ks2 < 2; ++ks2) {
            const int bb = 8 * ks2;
            unsigned a0 = pk2h(pv[bb + 0], pv[bb + 1]);
            unsigned a1 = pk2h(pv[bb + 2], pv[bb + 3]);
            unsigned a2 = pk2h(pv[bb + 4], pv[bb + 5]);
            unsigned a3 = pk2h(pv[bb + 6], pv[bb + 7]);
            pswap(a0, a2); pswap(a1, a3);
            union { unsigned int u[4]; h16x8 v; } pa;
            pa.u[0] = a0; pa.u[1] = a1; pa.u[2] = a2; pa.u[3] = a3;
            const int gv = 4 * wm + 2 * ks2 + h;
            __builtin_amdgcn_s_setprio(1);
            const h16x8 vb0 = ldfm(bVt, gv, c);
            const h16x8 vb1 = ldfm(bVt, gv, 32 + c);
            xacc[0] = MFMAH(pa.v, vb0, xacc[0]);
            xacc[1] = MFMAH(pa.v, vb1, xacc[1]);
            __builtin_amdgcn_s_setprio(0);
        }

        // rotate: A<-B (next compute), B<-D (in flight), D<-C (stage target), C<-A (retired)
        unsigned short* tmp = bufA;
        bufA = bufB; bufB = bufD; bufD = bufC; bufC = tmp;
    }
#undef STAGE

    __syncthreads();   // all compute done before epilogue aliases sT

    // ---- cross-wave (wm) reduction via LDS; scale exp2(-dq')*invn; write X ----
    if (wm == 0) {
        #pragma unroll
        for (int pt = 0; pt < 2; ++pt)
            #pragma unroll
            for (int r = 0; r < 16; ++r) {
                const int row = 32 * wq + (r & 3) + 8 * (r >> 2) + 4 * h;
                sXf[row * 64 + 32 * pt + c] = xacc[pt][r];
            }
    }
    __syncthreads();
    if (wm == 1) {
        float* Xh = Xg + (size_t)bh * NS * PD;
        #pragma unroll
        for (int pt = 0; pt < 2; ++pt)
            #pragma unroll
            for (int r = 0; r < 16; ++r) {
                const int row = 32 * wq + (r & 3) + 8 * (r >> 2) + 4 * h;
                const int col = 32 * pt + c;
                const float sc = fexp2(-sdQ[row] * LOG2E) * invn;
                Xh[(size_t)(n0 + row) * PD + col] = (sXf[row * 64 + col] + xacc[pt][r]) * sc;
            }
    }
}

// ---------------- fallback (R6 kernel, bf16 split) if ws too small ----------------
__global__ __launch_bounds__(256, 2) void kde_attn_fb(
    const float* __restrict__ Qg, const float* __restrict__ Kg,
    const float* __restrict__ Vg, const float* __restrict__ maskg,
    float* __restrict__ Xg)
{
    __shared__ __align__(16) unsigned short sKh[4096], sKl[4096], sVt[4096];
    __shared__ __align__(16) unsigned short sU[8192];
    __shared__ __align__(16) float scb[64];
    __shared__ float sdQ[64], red[4];

    unsigned short* const sQh = sU;
    unsigned short* const sQl = sU + 4096;

    const int t    = threadIdx.x;
    const int lane = t & 63;
    const int w    = t >> 6;
    const int h    = lane >> 5;
    const int c    = lane & 31;
    const int wm   = w >> 1;
    const int wq   = w & 1;

    const int s   = blockIdx.x;
    const int xcd = s & 7;
    const int ii  = s >> 3;
    const int bh  = 6 * xcd + (ii >> 5);
    const int n0  = (ii & 31) * 64;
    const int b   = bh / NH;

    const float DN = 0.42044820762685725f;

    const float* Qh = Qg + (size_t)bh * NS * PD;
    const float* Kh = Kg + (size_t)bh * NS * PD;
    const float* Vh = Vg + (size_t)bh * NS * PD;
    const float* mk = maskg + (size_t)b * NS;

    {
        float sm = 0.f;
        for (int i = t; i < NS; i += 256) sm += mk[i];
        #pragma unroll
        for (int m = 1; m < 64; m <<= 1) sm += __shfl_xor(sm, m);
        if (lane == 0) red[w] = sm;
    }

    #pragma unroll
    for (int j = 0; j < 4; ++j) {
        const int idx = j * 256 + t;
        const int row = idx >> 4;
        const int u   = idx & 15;
        const float qs = mk[n0 + row] * DN;
        float4 v = *(const float4*)(Qh + (size_t)(n0 + row) * PD + 4 * u);
        v.x *= qs; v.y *= qs; v.z *= qs; v.w *= qs;
        uint2 h4, l4; split4(v, h4, l4);
        const int iu = (row * 64 + 4 * u) ^ ((row & 7) << 3);
        *(uint2*)&sQh[iu] = h4;
        *(uint2*)&sQl[iu] = l4;
        float d = dot4(v);
        d += __shfl_xor(d, 1); d += __shfl_xor(d, 2);
        d += __shfl_xor(d, 4); d += __shfl_xor(d, 8);
        if (u == 0) sdQ[row] = 0.5f * d;
    }
    __syncthreads();

    const float npn  = red[0] + red[1] + red[2] + red[3];
    const float vscl = DN / npn;

    s16x8 qbh[4], qbl[4];
    #pragma unroll
    for (int ks = 0; ks < 4; ++ks) {
        const int kc = 16 * ks + 8 * h;
        qbh[ks] = ldfrag(sQh, 32 * wq + c, kc);
        qbl[ks] = ldfrag(sQl, 32 * wq + c, kc);
    }
    const float dq = sdQ[32 * wq + c];

    f32x16 xacc[2];
    #pragma unroll
    for (int pt = 0; pt < 2; ++pt)
        #pragma unroll
        for (int r = 0; r < 16; ++r) xacc[pt][r] = 0.f;

    for (int mt = 0; mt < NS / 64; ++mt) {
        const int m0 = mt * 64;

        #pragma unroll
        for (int j = 0; j < 4; ++j) {
            const int idx = j * 256 + t;
            const int row = idx >> 4;
            const int u   = idx & 15;
            const float mr  = mk[m0 + row];
            const float ksc = mr * DN;
            float4 v = *(const float4*)(Kh + (size_t)(m0 + row) * PD + 4 * u);
            v.x *= ksc; v.y *= ksc; v.z *= ksc; v.w *= ksc;
            uint2 h4, l4; split4(v, h4, l4);
            const int iu = (row * 64 + 4 * u) ^ ((row & 7) << 3);
            *(uint2*)&sKh[iu] = h4;
            *(uint2*)&sKl[iu] = l4;
            float d = dot4(v);
            d += __shfl_xor(d, 1); d += __shfl_xor(d, 2);
            d += __shfl_xor(d, 4); d += __shfl_xor(d, 8);
            if (u == 0) scb[row] = fmaf(-1.0e9f, 1.f - mr, -0.5f * d);
        }
        #pragma unroll
        for (int j = 0; j < 4; ++j) {
            const int p  = lane;
            const int mq = 4 * j + ((w + (p >> 3)) & 3);
            const float* vc = Vh + (size_t)(m0 + 4 * mq) * PD + p;
            float4 mr = *(const float4*)&mk[m0 + 4 * mq];
            float4 v = make_float4(vc[0] * (mr.x * vscl), vc[PD] * (mr.y * vscl),
                                   vc[2 * PD] * (mr.z * vscl), vc[3 * PD] * (mr.w * vscl));
            *(uint2*)&sVt[(p * 64 + 4 * mq) ^ ((p & 7) << 3)] = cvt4h(v);
        }
        __syncthreads();

        f32x16 acc;
        #pragma unroll
        for (int r = 0; r < 16; ++r) acc[r] = 0.f;

        __builtin_amdgcn_s_setprio(1);
        #pragma unroll
        for (int ks = 0; ks < 4; ++ks) {
            const int kc = 16 * ks + 8 * h;
            const s16x8 kh = ldfrag(sKh, 32 * wm + c, kc);
            const s16x8 kl = ldfrag(sKl, 32 * wm + c, kc);
            acc = MFMAB(kh, qbh[ks], acc);
            acc = MFMAB(kh, qbl[ks], acc);
            acc = MFMAB(kl, qbh[ks], acc);
        }
        __builtin_amdgcn_s_setprio(0);

        float pv[16];
        #pragma unroll
        for (int g = 0; g < 4; ++g) {
            const f32x4 cb4 = *(const f32x4*)&scb[32 * wm + 8 * g + 4 * h];
            #pragma unroll
            for (int e = 0; e < 4; ++e)
                pv[4 * g + e] = __expf(acc[4 * g + e] - dq + cb4[e]);
        }

        #pragma unroll
        for (int ks2 = 0; ks2 < 2; ++ks2) {
            const int bb = 8 * ks2;
            unsigned w0 = pk2(pv[bb + 0], pv[bb + 1]);
            unsigned w1 = pk2(pv[bb + 2], pv[bb + 3]);
            unsigned w2 = pk2(pv[bb + 4], pv[bb + 5]);
            unsigned w3 = pk2(pv[bb + 6], pv[bb + 7]);
            pswap(w0, w2);
            pswap(w1, w3);
            union { unsigned int u[4]; s16x8 v; } pa;
            pa.u[0] = w0; pa.u[1] = w1; pa.u[2] = w2; pa.u[3] = w3;
            const int kc = 32 * wm + 16 * ks2 + 8 * h;
            __builtin_amdgcn_s_setprio(1);
            #pragma unroll
            for (int pt = 0; pt < 2; ++pt) {
                const s16x8 vb = ldfrag(sVt, 32 * pt + c, kc);
                xacc[pt] = MFMAB(pa.v, vb, xacc[pt]);
            }
            __builtin_amdgcn_s_setprio(0);
        }
        __syncthreads();
    }

    float* sX = (float*)sU;
    if (wm == 0) {
        #pragma unroll
        for (int pt = 0; pt < 2; ++pt)
            #pragma unroll
            for (int r = 0; r < 16; ++r) {
                const int row = 32 * wq + (r & 3) + 8 * (r >> 2) + 4 * h;
                sX[row * 64 + 32 * pt + c] = xacc[pt][r];
            }
    }
    __syncthreads();
    if (wm == 1) {
        float* Xh = Xg + (size_t)bh * NS * PD;
        #pragma unroll
        for (int pt = 0; pt < 2; ++pt)
            #pragma unroll
            for (int r = 0; r < 16; ++r) {
                const int row = 32 * wq + (r & 3) + 8 * (r >> 2) + 4 * h;
                const int col = 32 * pt + c;
                Xh[(size_t)(n0 + row) * PD + col] = sX[row * 64 + col] + xacc[pt][r];
            }
    }
}

extern "C" void kernel_launch(void* const* d_in, const int* in_sizes, int n_in,
                              void* d_out, int out_size, void* d_ws, size_t ws_size,
                              hipStream_t stream) {
    const float* Q    = (const float*)d_in[0];
    const float* K    = (const float*)d_in[1];
    const float* V    = (const float*)d_in[2];
    const float* mask = (const float*)d_in[3];
    float* X = (float*)d_out;

    const size_t need = (size_t)NB * NH * 32 * CHUNK;   // 25.6 MB
    if (d_ws != nullptr && ws_size >= need) {
        kde_pre<<<dim3(NB * NH * 32), dim3(256), 0, stream>>>(K, V, mask, (unsigned char*)d_ws);
        kde_main<<<dim3(NB * NH * 16), dim3(512), 0, stream>>>(Q, mask, (const unsigned char*)d_ws, X);
    } else {
        kde_attn_fb<<<dim3(NB * NH * 32), dim3(256), 0, stream>>>(Q, K, V, mask, X);
    }
}